// Round 9
// baseline (185.913 us; speedup 1.0000x reference)
//
#include <hip/hip_runtime.h>
#include <hip/hip_bf16.h>
#include <stdint.h>

typedef __attribute__((ext_vector_type(8))) short short8;   // bf16x8 MFMA frag
typedef __attribute__((ext_vector_type(16))) float f32x16;  // 32x32 accumulator

#define NB 8
#define NN 2048
#define NF 128
#define NK 4096
#define L2E 1.4426950408889634f

// ---- workspace layout (bytes) ----
#define OFF_HT   0u            // hT[2][8][128][4096] bf16 (col-major h) = 16777216
#define OFF_WCT  16777216u     // WcT[128][128] bf16 (col-major)
#define OFF_WFT  16809984u
#define OFF_WST  16842752u
#define OFF_U1   16875520u     // u1[128] f32 = Wf @ a_q
#define OFF_U2   16876032u     // u2[128] f32 = Wc @ a_k
#define OFF_U3   16876544u     // u3[128] f32 = Wf @ a_k
#define OFF_SQ   16877056u     // sq'[2][8][2048] f32  (pre-scaled by log2e)
#define OFF_SK   17008128u     // sk'[2][8][4096] f32  (pre-scaled by log2e)
// total 17270272 (~16.5 MiB)

__device__ __forceinline__ short f2bf(float f){
  __bf16 h = (__bf16)f;
  return __builtin_bit_cast(short, h);
}
__device__ __forceinline__ short8 pack8(float4 a, float4 b){
  short8 r;
  r[0]=f2bf(a.x); r[1]=f2bf(a.y); r[2]=f2bf(a.z); r[3]=f2bf(a.w);
  r[4]=f2bf(b.x); r[5]=f2bf(b.y); r[6]=f2bf(b.z); r[7]=f2bf(b.w);
  return r;
}

typedef const __attribute__((address_space(1))) unsigned int* gas_t;
typedef __attribute__((address_space(3))) unsigned int* las_t;
__device__ __forceinline__ void gload_lds16(const void* g, void* l){
  // LDS dest is wave-uniform base; HW writes lane i at base + i*16.
  __builtin_amdgcn_global_load_lds((gas_t)g, (las_t)l, 16, 0, 0);
}

// ---------------- kernel 0: weight prep (parallel) ----------------
__global__ __launch_bounds__(256) void k_prep(const float* __restrict__ Wc,
                                              const float* __restrict__ Wf,
                                              const float* __restrict__ Ws,
                                              const float* __restrict__ att,
                                              char* __restrict__ ws){
  int bidx = blockIdx.x, tid = threadIdx.x;
  if (bidx < 12){
    __shared__ float tile[32][129];
    int m = bidx >> 2, tno = bidx & 3;
    const float* W = (m == 0) ? Wc : ((m == 1) ? Wf : Ws);
    short* WT = (short*)(ws + ((m == 0) ? OFF_WCT : ((m == 1) ? OFF_WFT : OFF_WST)));
    int r0 = tno*32;
    #pragma unroll
    for (int i = 0; i < 16; i++){
      int e = tid + i*256;
      tile[e >> 7][e & 127] = W[(r0 + (e >> 7))*NF + (e & 127)];
    }
    __syncthreads();
    #pragma unroll
    for (int i = 0; i < 16; i++){
      int o = tid + i*256;
      int col = o >> 5, rr = o & 31;
      WT[col*NF + r0 + rr] = f2bf(tile[rr][col]);
    }
  } else {
    int wid = tid >> 6, lane = tid & 63;
    float aq0 = att[lane],      aq1 = att[64 + lane];
    float ak0 = att[NF + lane], ak1 = att[NF + 64 + lane];
    float* u1 = (float*)(ws + OFF_U1);
    float* u2 = (float*)(ws + OFF_U2);
    float* u3 = (float*)(ws + OFF_U3);
    for (int j = 0; j < 32; j++){
      int r = wid*32 + j;
      float wf0 = Wf[r*NF + lane], wf1 = Wf[r*NF + 64 + lane];
      float wc0 = Wc[r*NF + lane], wc1 = Wc[r*NF + 64 + lane];
      float s1 = wf0*aq0 + wf1*aq1;
      float s2 = wc0*ak0 + wc1*ak1;
      float s3 = wf0*ak0 + wf1*ak1;
      #pragma unroll
      for (int d = 1; d < 64; d <<= 1){
        s1 += __shfl_xor(s1, d); s2 += __shfl_xor(s2, d); s3 += __shfl_xor(s3, d);
      }
      if (lane == 0){ u1[r] = s1; u2[r] = s2; u3[r] = s3; }
    }
  }
}

// ---------------- kernel 1: build hT (bf16 col-major) + scaled s vectors ----------------
__global__ __launch_bounds__(256) void k_build(const float* __restrict__ x1,
                                               const float* __restrict__ x2,
                                               char* __restrict__ ws){
  int bid = blockIdx.x;
  int xid  = bid >> 7;
  int b    = (bid >> 4) & 7;
  int tile = bid & 15;
  int tid = threadIdx.x, wid = tid >> 6, lane = tid & 63;
  int l31 = lane & 31, khalf = lane >> 5;
  int r0 = tile*128 + wid*32;
  int row = r0 + l31;

  const float* x = xid ? x2 : x1;
  const float* u1 = (const float*)(ws + OFF_U1);
  const float* u2 = (const float*)(ws + OFF_U2);
  const float* u3 = (const float*)(ws + OFF_U3);
  const float* xrow = x + (size_t)(b*NN + row)*NF;

  short8 aF[8];
  float p1=0.f, p2=0.f, p3=0.f;
  #pragma unroll
  for (int ks = 0; ks < 8; ks++){
    int k0 = ks*16 + khalf*8;
    float4 xa = *(const float4*)(xrow + k0);
    float4 xb = *(const float4*)(xrow + k0 + 4);
    float4 a1 = *(const float4*)(u1 + k0), b1 = *(const float4*)(u1 + k0 + 4);
    float4 a2 = *(const float4*)(u2 + k0), b2 = *(const float4*)(u2 + k0 + 4);
    float4 a3 = *(const float4*)(u3 + k0), b3 = *(const float4*)(u3 + k0 + 4);
    p1 += xa.x*a1.x + xa.y*a1.y + xa.z*a1.z + xa.w*a1.w
        + xb.x*b1.x + xb.y*b1.y + xb.z*b1.z + xb.w*b1.w;
    p2 += xa.x*a2.x + xa.y*a2.y + xa.z*a2.z + xa.w*a2.w
        + xb.x*b2.x + xb.y*b2.y + xb.z*b2.z + xb.w*b2.w;
    p3 += xa.x*a3.x + xa.y*a3.y + xa.z*a3.z + xa.w*a3.w
        + xb.x*b3.x + xb.y*b3.y + xb.z*b3.z + xb.w*b3.w;
    aF[ks] = pack8(xa, xb);
  }
  p1 += __shfl_xor(p1, 32);
  p2 += __shfl_xor(p2, 32);
  p3 += __shfl_xor(p3, 32);
  if (lane < 32){
    float* sq = (float*)(ws + OFF_SQ);
    float* sk = (float*)(ws + OFF_SK);
    sq[(xid*NB + b)*NN + row] = p1*L2E;            // s_q' of own set
    sk[(xid*NB + b)*NK + NN + row] = p3*L2E;       // friend-half s_k' of own set
    sk[((1 - xid)*NB + b)*NK + row] = p2*L2E;      // cross-half s_k' of other set
  }

  short* hT = (short*)(ws + OFF_HT);
  #pragma unroll
  for (int g = 0; g < 2; g++){
    const short* W = g ? (const short*)(ws + OFF_WFT) : (const short*)(ws + OFF_WCT);
    int dset = g ? xid : (1 - xid);
    int kb2  = (g ? NN : 0) + r0;
    f32x16 acc[4] = {};
    #pragma unroll
    for (int ks = 0; ks < 8; ks++){
      #pragma unroll
      for (int cb = 0; cb < 4; cb++){
        short8 bF = *(const short8*)(W + (cb*32 + l31)*NF + ks*16 + khalf*8);
        acc[cb] = __builtin_amdgcn_mfma_f32_32x32x16_bf16(aF[ks], bF, acc[cb], 0, 0, 0);
      }
    }
    short* hbase = hT + (size_t)(dset*NB + b)*NF*NK;
    #pragma unroll
    for (int cb = 0; cb < 4; cb++){
      short* hc = hbase + (size_t)(cb*32 + l31)*NK;
      #pragma unroll
      for (int g4 = 0; g4 < 4; g4++){
        int kr = kb2 + g4*8 + khalf*4;
        uint2 v;
        v.x = (unsigned)(unsigned short)f2bf(acc[cb][4*g4+0]) |
              ((unsigned)(unsigned short)f2bf(acc[cb][4*g4+1]) << 16);
        v.y = (unsigned)(unsigned short)f2bf(acc[cb][4*g4+2]) |
              ((unsigned)(unsigned short)f2bf(acc[cb][4*g4+3]) << 16);
        *(uint2*)(hc + kr) = v;
      }
    }
  }
}

// ---------------- kernel 2: fused softmax-weighted GEMM + self ----------------
// grid 512 (64q tiles), 256 thr = 4 waves = 4 PRIVATE k-groups (1024 keys each).
// No block barriers in main loop: each wave stages its own 16KB chunk and
// consumes it alone (single-buffer, vmcnt(0) per chunk). rb=2 -> acc[2][4].
// 2 blocks/CU (66KB LDS), 8 free-running waves/CU.
__global__ __launch_bounds__(256, 2) void k_attn(const float* __restrict__ x1,
                                                 const float* __restrict__ x2,
                                                 const char* __restrict__ ws,
                                                 float* __restrict__ out){
  __shared__ __align__(16) char stg[4][16384];   // per-wave private chunk buffer
  __shared__ float zl[4][2][64];                 // Z partials per wave

  int hw = blockIdx.x;
  int bid = (hw & 7)*64 + (hw >> 3);             // XCD-aware swizzle (512 = 8*64)
  int set = bid >> 8, b = (bid >> 5) & 7, qt = bid & 31;
  int tid = threadIdx.x, g = tid >> 6, lane = tid & 63;
  int l31 = lane & 31, khalf = lane >> 5;

  const short* hT  = (const short*)(ws + OFF_HT) + (size_t)(set*NB + b)*NF*NK;
  const float* skg = (const float*)(ws + OFF_SK) + (set*NB + b)*NK;
  const float* sqg = (const float*)(ws + OFF_SQ) + (set*NB + b)*NN;
  const short* WsT = (const short*)(ws + OFF_WST);

  // per-lane staging source offsets (in shorts), constant across chunks
  int soff[16];
  #pragma unroll
  for (int i = 0; i < 16; i++){
    int u = i*64 + lane;                          // 16B unit id 0..1023
    int col = u >> 3, k16 = u & 7;
    soff[i] = col*NK + (k16 ^ (col & 7))*8;       // pre-swizzled source
  }

  // per-wave skmax (register scan of 16KB, coalesced)
  float mx = -3.0e38f;
  #pragma unroll
  for (int i = 0; i < 16; i++){
    float4 v = *(const float4*)(skg + i*256 + lane*4);
    mx = fmaxf(mx, fmaxf(fmaxf(v.x, v.y), fmaxf(v.z, v.w)));
  }
  #pragma unroll
  for (int d = 1; d < 64; d <<= 1) mx = fmaxf(mx, __shfl_xor(mx, d));
  float skmax = mx;

  int q0w = qt*64;
  float sqm[2], c9[2]; int kdiag[2];
  #pragma unroll
  for (int rb = 0; rb < 2; rb++){
    int row = q0w + rb*32 + l31;
    float sqv = sqg[row];                         // sq' (scaled by log2e)
    float t0 = sqv + skmax;
    float moff = fmaxf(t0, 0.1f*t0);              // exact row max of lrelu (scaled)
    sqm[rb] = sqv - moff;
    c9[rb]  = -0.9f*moff;
    kdiag[rb] = NN + row;
  }
  int chd = (NN + q0w) >> 6;                      // both rb diag rows in this chunk

  f32x16 acc[2][4] = {};
  float zacc[2] = {0.f, 0.f};
  char* buf = stg[g];
  int rdswz = l31 & 7;                            // read-slot XOR

  for (int it = 0; it < 16; ++it){
    int ch = g*16 + it;
    // all ds_reads of previous chunk retired before DMA overwrites buffer
    asm volatile("s_waitcnt lgkmcnt(0)" ::: "memory");
    __builtin_amdgcn_sched_barrier(0);
    const short* hsrc = hT + ch*64;
    #pragma unroll
    for (int i = 0; i < 16; i++)
      gload_lds16((const void*)(hsrc + soff[i]), (void*)(buf + i*1024));
    asm volatile("s_waitcnt vmcnt(0)" ::: "memory");
    __builtin_amdgcn_sched_barrier(0);

    #pragma unroll
    for (int ks = 0; ks < 4; ks++){
      const float* skp = skg + ch*64 + ks*16 + khalf*8;
      float4 sa = *(const float4*)skp;
      float4 sb = *(const float4*)(skp + 4);
      float sv[8] = {sa.x, sa.y, sa.z, sa.w, sb.x, sb.y, sb.z, sb.w};
      int kg0 = ch*64 + ks*16 + khalf*8;
      short8 aw[2];
      #pragma unroll
      for (int rb = 0; rb < 2; rb++){
        float wv[8];
        #pragma unroll
        for (int j = 0; j < 8; j++){
          float p = sv[j] + sqm[rb];                   // t' - moff
          float qn = __builtin_fmaf(0.1f, p, c9[rb]);  // 0.1 t' - moff
          wv[j] = __builtin_amdgcn_exp2f(fmaxf(p, qn));
        }
        if (ch == chd){                                // zero masked diagonal
          #pragma unroll
          for (int j = 0; j < 8; j++) wv[j] = (kg0 + j == kdiag[rb]) ? 0.f : wv[j];
        }
        #pragma unroll
        for (int j = 0; j < 8; j++) zacc[rb] += wv[j];
        #pragma unroll
        for (int j = 0; j < 8; j++) aw[rb][j] = f2bf(wv[j]);
      }
      int slot = (ks*2 + khalf) ^ rdswz;
      #pragma unroll
      for (int cb = 0; cb < 4; cb++){
        short8 bF = *(const short8*)(buf + (cb*32 + l31)*128 + slot*16);
        acc[0][cb] = __builtin_amdgcn_mfma_f32_32x32x16_bf16(aw[0], bF, acc[0][cb], 0, 0, 0);
        acc[1][cb] = __builtin_amdgcn_mfma_f32_32x32x16_bf16(aw[1], bF, acc[1][cb], 0, 0, 0);
      }
    }
  }

  // ---- combine: cb-redistribution across the 4 waves (2 rb rounds) ----
  zl[g][0][lane] = zacc[0];
  zl[g][1][lane] = zacc[1];
  float* comb = (float*)stg;                      // [cb:4][src:4][r:16][lane:64]
  f32x16 accF[2];
  #pragma unroll
  for (int rb = 0; rb < 2; rb++){
    __syncthreads();                              // stg free / prev round read done
    #pragma unroll
    for (int c = 0; c < 4; c++)
      #pragma unroll
      for (int r = 0; r < 16; r++)
        comb[((c*4 + g)*16 + r)*64 + lane] = acc[rb][c][r];
    __syncthreads();
    #pragma unroll
    for (int r = 0; r < 16; r++){
      float s = 0.f;
      #pragma unroll
      for (int src = 0; src < 4; src++)
        s += comb[((g*4 + src)*16 + r)*64 + lane];
      accF[rb][r] = s;
    }
  }

  // ---- epilogue: each wave owns cb=g (cols g*32..g*32+31) ----
  const float* x = set ? x2 : x1;
  float* op = out + (size_t)(set*NB + b)*NN*NF;
  #pragma unroll
  for (int rb = 0; rb < 2; rb++){
    float zfull = 0.f;
    #pragma unroll
    for (int w = 0; w < 4; w++) zfull += zl[w][rb][l31] + zl[w][rb][l31 + 32];
    float rz = 1.0f / zfull;
    float rzv[16];
    #pragma unroll
    for (int r = 0; r < 16; r++){
      int rowc = (r & 3) + 8*(r >> 2) + 4*khalf;
      rzv[r] = __shfl(rz, rowc);
    }
    #pragma unroll
    for (int r = 0; r < 16; r++) accF[rb][r] *= rzv[r];

    const float* xrow = x + (size_t)(b*NN + q0w + rb*32 + l31)*NF;
    #pragma unroll
    for (int ks8 = 0; ks8 < 8; ks8++){
      int k0 = ks8*16 + khalf*8;
      float4 xa = *(const float4*)(xrow + k0);
      float4 xb = *(const float4*)(xrow + k0 + 4);
      short8 aF = pack8(xa, xb);
      short8 bF = *(const short8*)(WsT + (g*32 + l31)*NF + k0);
      accF[rb] = __builtin_amdgcn_mfma_f32_32x32x16_bf16(aF, bF, accF[rb], 0, 0, 0);
    }
    #pragma unroll
    for (int r = 0; r < 16; r++){
      int rowc = (r & 3) + 8*(r >> 2) + 4*khalf;
      op[(size_t)(q0w + rb*32 + rowc)*NF + g*32 + l31] = accF[rb][r];
    }
  }
}

extern "C" void kernel_launch(void* const* d_in, const int* in_sizes, int n_in,
                              void* d_out, int out_size, void* d_ws, size_t ws_size,
                              hipStream_t stream){
  const float* x1  = (const float*)d_in[0];
  const float* x2  = (const float*)d_in[1];
  const float* Wc  = (const float*)d_in[2];
  const float* Wf  = (const float*)d_in[3];
  const float* Ws  = (const float*)d_in[4];
  const float* att = (const float*)d_in[5];
  char* ws = (char*)d_ws;
  float* out = (float*)d_out;

  k_prep<<<dim3(13),  dim3(256), 0, stream>>>(Wc, Wf, Ws, att, ws);
  k_build<<<dim3(256), dim3(256), 0, stream>>>(x1, x2, ws);
  k_attn<<<dim3(512), dim3(256), 0, stream>>>(x1, x2, ws, out);
}